// Round 9
// baseline (191.771 us; speedup 1.0000x reference)
//
#include <hip/hip_runtime.h>
#include <math.h>

// Problem constants
#define Bn    64
#define Cn    3
#define IMG   224
#define PLANE (IMG*IMG)      // 50176
#define C1    6
#define P1    110            // conv1(220) + maxpool2 -> 110
#define P2    106            // conv2 output spatial
#define NVALID (P2*P2)       // 11236
#define Hh    32
#define Ww    64
#define UPR   10
#define UPT   10
#define Hg    (Hh*UPR)       // 320
#define Wg    (Ww*UPT)       // 640
#define POOLED_SIZE (Bn*Cn*Hh*Ww)   // 393216
#define RPB   4
#define NCHUNK 28            // 28 chunks of 4 pooled rows
#define PCHUNK (NCHUNK * RPB)           // 112 per-wave partial slots
#define PSTRIDE 152

typedef unsigned short u16;
typedef unsigned int   u32;
typedef float v2f __attribute__((ext_vector_type(2)));

// workspace: partials (B*112*152 f32) | wt (B*2 f32, fallback only) | x4b bf16
#define PART_FLOATS ((size_t)Bn * PCHUNK * PSTRIDE)
#define X4B_U16     ((size_t)Bn * PLANE * 4)
#define WS_NEEDED   ((PART_FLOATS + Bn * 2) * 4 + X4B_U16 * 2)

__device__ __forceinline__ u16 f2bf(float f) {
    union { u32 u; float f; } c; c.f = f;
    u32 r = c.u + 0x7fffu + ((c.u >> 16) & 1u);   // RNE
    return (u16)(r >> 16);
}
__device__ __forceinline__ float bf2f(u16 v) {
    union { u32 u; float f; } c; c.u = ((u32)v) << 16;
    return c.f;
}

// 7 overlapping pairs P[j] = (r[j], r[j+1]) from an 8-float LDS row segment.
__device__ __forceinline__ void load_pairs(v2f* P, const float* rp) {
    const float4 a = *(const float4*)rp;
    const float4 c = *(const float4*)(rp + 4);
    P[0] = (v2f){a.x, a.y};
    P[1] = (v2f){a.y, a.z};
    P[2] = (v2f){a.z, a.w};
    P[3] = (v2f){a.w, c.x};
    P[4] = (v2f){c.x, c.y};
    P[5] = (v2f){c.y, c.z};
    P[6] = (v2f){c.z, c.w};
}

// -------------------------------------------------------------------------
// K1: fused conv1 (6 OCs, v_pk_fma_f32) + maxpool2 + bf16-NHWC4 repack +
// shuffle window sums -> per-wave partials. SINGLE 20-row staging serves
// both 4-row chunks of this block (rows overlap), so the block has exactly
// ONE barrier (post-stage) — R8 had 4. Grid (14,64); block owns pooled rows
// [8q, 8q+8) and input rows [16q, 16q+20).
// -------------------------------------------------------------------------
__global__ __launch_bounds__(256) void k1_fused(
    const float* __restrict__ x,      // (B,3,224,224)
    const float* __restrict__ w1,     // (6,3,5,5)
    const float* __restrict__ b1,     // (6,)
    float* __restrict__ partial,      // (B,112,PSTRIDE) per-wave
    u16* __restrict__ x4b,            // (B,224,224,4) bf16 out
    int do_pack)
{
    __shared__ __attribute__((aligned(16))) float xs[3][20][224];  // 53760 B

    const int b    = blockIdx.y;
    const int q    = blockIdx.x;      // 0..13
    const int tid  = threadIdx.x;
    const int wid  = tid >> 6;
    const int lane = tid & 63;

    const float* xb = x + (size_t)b * (Cn * PLANE);
    const int gybase = 16 * q;

    // stage 20 input rows x 3 ic, coalesced float4: 3*20*56 = 3360 vec4
    for (int i = tid; i < 3 * 20 * 56; i += 256) {
        const int ic  = i / (20 * 56);
        const int rem = i - ic * (20 * 56);
        const int r   = rem / 56;
        const int c4  = rem - r * 56;
        const int gy  = gybase + r;
        if (gy < IMG)
            *(float4*)(&xs[ic][r][c4 * 4]) =
                *(const float4*)(xb + ic * PLANE + gy * IMG + c4 * 4);
    }
    __syncthreads();   // the ONLY barrier in this kernel

    // bf16 NHWC4 pack of this block's 16 owned rows (14 blocks x 16 = 224)
    if (do_pack) {
        u16* ob = x4b + (size_t)b * PLANE * 4;
        for (int i = tid; i < 16 * IMG; i += 256) {
            const int r   = i / IMG;
            const int col = i - r * IMG;
            const int gy  = gybase + r;
            ushort4 v;
            v.x = f2bf(xs[0][r][col]);
            v.y = f2bf(xs[1][r][col]);
            v.z = f2bf(xs[2][r][col]);
            v.w = 0;
            *(ushort4*)(ob + ((size_t)gy * IMG + col) * 4) = v;
        }
    }

    #pragma unroll
    for (int c = 0; c < 2; ++c) {
        const int y = 8 * q + 4 * c + wid;          // pooled row
        const int rowbase = 2 * wid + 8 * c;        // local xs row of conv row 2y
        const bool rowvalid = (y < P1);
        const bool active = (lane < 55) && rowvalid;

        float pp0[C1], pp1[C1];
        if (active) {
            v2f accT01[C1], accT23[C1], accB01[C1], accB23[C1];
            #pragma unroll
            for (int oc = 0; oc < C1; ++oc) {
                const float bv = b1[oc];
                const v2f bvv = (v2f){bv, bv};
                accT01[oc] = bvv; accT23[oc] = bvv;
                accB01[oc] = bvv; accB23[oc] = bvv;
            }

            #pragma unroll
            for (int ic = 0; ic < 3; ++ic) {
                v2f Pa[7], Pb[7];
                load_pairs(Pa, &xs[ic][rowbase][4 * lane]);
                load_pairs(Pb, &xs[ic][rowbase + 1][4 * lane]);
                #pragma unroll
                for (int ky = 0; ky < 5; ++ky) {
                    const v2f* Pt = (ky & 1) ? Pb : Pa;   // conv row 2y+ky
                    const v2f* Po = (ky & 1) ? Pa : Pb;   // conv row 2y+ky+1
                    #pragma unroll
                    for (int oc = 0; oc < C1; ++oc) {
                        const float* wrow = w1 + ((oc * 3 + ic) * 25 + ky * 5);
                        #pragma unroll
                        for (int kx = 0; kx < 5; ++kx) {
                            const float wv = wrow[kx];     // uniform s_load
                            const v2f wvv = (v2f){wv, wv};
                            accT01[oc] += Pt[kx]     * wvv;  // v_pk_fma_f32
                            accT23[oc] += Pt[kx + 2] * wvv;
                            accB01[oc] += Po[kx]     * wvv;
                            accB23[oc] += Po[kx + 2] * wvv;
                        }
                    }
                    if (ky < 4)
                        load_pairs((ky & 1) ? Pb : Pa,
                                   &xs[ic][rowbase + ky + 2][4 * lane]);
                }
            }

            #pragma unroll
            for (int oc = 0; oc < C1; ++oc) {
                pp0[oc] = fmaxf(fmaxf(accT01[oc].x, accT01[oc].y),
                                fmaxf(accB01[oc].x, accB01[oc].y));
                pp1[oc] = fmaxf(fmaxf(accT23[oc].x, accT23[oc].y),
                                fmaxf(accB23[oc].x, accB23[oc].y));
            }
        } else {
            #pragma unroll
            for (int oc = 0; oc < C1; ++oc) { pp0[oc] = 0.0f; pp1[oc] = 0.0f; }
        }

        // Wave-level windowed row sums -> per-wave global partial slot.
        float* dst = partial +
            ((size_t)b * PCHUNK + (2 * q + c) * RPB + wid) * PSTRIDE;
        #pragma unroll
        for (int oc = 0; oc < C1; ++oc) {
            float s = pp0[oc] + pp1[oc];
            #pragma unroll
            for (int off = 32; off > 0; off >>= 1) s += __shfl_xor(s, off, 64);
            const float c0   = __shfl(pp0[oc], 0, 64);
            const float c1   = __shfl(pp1[oc], 0, 64);
            const float c2   = __shfl(pp0[oc], 1, 64);
            const float c3   = __shfl(pp1[oc], 1, 64);
            const float c106 = __shfl(pp0[oc], 53, 64);
            const float c107 = __shfl(pp1[oc], 53, 64);
            const float c108 = __shfl(pp0[oc], 54, 64);
            const float c109 = __shfl(pp1[oc], 54, 64);
            const float w0v = s - (c106 + c107 + c108 + c109);
            const float w1v = s - c0 - (c107 + c108 + c109);
            const float w2v = s - (c0 + c1) - (c108 + c109);
            const float w3v = s - (c0 + c1 + c2) - c109;
            const float w4v = s - (c0 + c1 + c2 + c3);
            if (lane < 25) {
                const int ky = lane / 5;
                const int kx = lane % 5;
                float wv = w0v;
                wv = (kx == 1) ? w1v : wv;
                wv = (kx == 2) ? w2v : wv;
                wv = (kx == 3) ? w3v : wv;
                wv = (kx == 4) ? w4v : wv;
                const bool valid = rowvalid && ((unsigned)(y - ky) <= 105u);
                dst[oc * 25 + lane] = valid ? wv : 0.0f;
            }
        }
    }
}

// -------------------------------------------------------------------------
// Clamp-coordinate sampling (equivalent to corner-clamp border mode).
// -------------------------------------------------------------------------
__device__ __forceinline__ void sample_coords(
    float gxn, float gyn, int& x0, int& y0, float& wx, float& wy)
{
    float ix = ((gxn + 1.0f) * (float)IMG - 1.0f) * 0.5f;
    float iy = ((gyn + 1.0f) * (float)IMG - 1.0f) * 0.5f;
    ix = fminf(fmaxf(ix, 0.0f), (float)(IMG - 1));
    iy = fminf(fmaxf(iy, 0.0f), (float)(IMG - 1));
    x0 = (int)ix; if (x0 > IMG - 2) x0 = IMG - 2;
    y0 = (int)iy; if (y0 > IMG - 2) y0 = IMG - 2;
    wx = ix - (float)x0;
    wy = iy - (float)y0;
}

// -------------------------------------------------------------------------
// K3 (fused head + bf16 NHWC4 sample + pool): each block redundantly
// computes the head for its b (reduce 112 partials with 600 threads +
// wave-0 shuffle MLP — ~7 kFLOP, trivial), then samples. Kills the k2
// dispatch. XCD swizzle (R5): b = (L&7) + 8*(L>>8). ushort4 2x8B loads
// (R7-proven; R8's dwordx4 regressed).
// -------------------------------------------------------------------------
__global__ __launch_bounds__(640) void k3_fused(
    const u16* __restrict__ x4b,      // (B,224,224,4) bf16
    const float* __restrict__ ltp,
    const float* __restrict__ partial,
    const float* __restrict__ w2, const float* __restrict__ b2,
    const float* __restrict__ fc1w, const float* __restrict__ fc1b,
    const float* __restrict__ fc2w, const float* __restrict__ fc2b,
    float* __restrict__ out)
{
    __shared__ float part[3 * Wg];    // 7680 B
    __shared__ float red[4][150];     // 2400 B
    __shared__ float wsb[150];
    __shared__ float wt2[2];

    const int L = blockIdx.x;         // 0..2047
    const int qq = L >> 3;            // 0..255
    const int h = qq & 31;
    const int b = (L & 7) + 8 * (qq >> 5);
    const int tid = threadIdx.x;

    // Per-thread trig first (independent of head result)
    const float angle = 6.283185307179586f * (float)tid / (float)Wg;
    const float sn = __sinf(angle);
    const float cs = __cosf(angle);

    // ---- fused head: reduce 112 per-wave partials (4 groups x 28) ----
    if (tid < 600) {
        const int g = tid / 150;
        const int e = tid - g * 150;
        const float* p = partial + ((size_t)b * PCHUNK + g * 28) * PSTRIDE + e;
        float s = 0.0f;
        #pragma unroll 7
        for (int c = 0; c < 28; ++c) s += p[c * PSTRIDE];
        red[g][e] = s;
    }
    __syncthreads();
    if (tid < 150)
        wsb[tid] = red[0][tid] + red[1][tid] + red[2][tid] + red[3][tid];
    __syncthreads();
    if (tid < 64) {                   // wave 0 computes the MLP via shuffles
        const int fi = tid & 15;
        float s = 0.0f;
        for (int j = 0; j < 150; ++j) s += w2[fi * 150 + j] * wsb[j];
        const float feat = b2[fi] + s * (1.0f / (float)NVALID);
        const int hi = tid & 7;
        float s1 = fc1b[hi];
        #pragma unroll
        for (int j = 0; j < 16; ++j) s1 += fc1w[hi * 16 + j] * __shfl(feat, j, 64);
        const float hv = fmaxf(s1, 0.0f);
        const int oi = tid & 1;
        float s2 = fc2b[oi];
        #pragma unroll
        for (int j = 0; j < 8; ++j) s2 += fc2w[oi * 8 + j] * __shfl(hv, j, 64);
        const float sig = (s2 >= 0.0f) ? (1.0f / (1.0f + __expf(-s2)))
                                       : (__expf(s2) / (1.0f + __expf(s2)));
        const float wgt = 5.0f * sig;
        if (tid < 2) {
            wt2[tid] = wgt;
            if (h == 0) out[POOLED_SIZE + b * 2 + tid] = wgt;   // weight output
        }
    }
    __syncthreads();

    const float w0 = wt2[0];
    const float w1 = wt2[1];
    const float l0 = ltp[b * 2 + 0];
    const float l1 = ltp[b * 2 + 1];
    const float start = __logf(0.01f * w0);
    const float stop  = __logf(0.6f  * w1);
    const float dr = stop - start;

    const u16* xb4 = x4b + (size_t)b * PLANE * 4;

    const float ratio = __expf(dr * (1.0f / (float)(Hg - 1)));
    float r = __expf(start + dr * ((float)(h * UPR) / (float)(Hg - 1)));

    float acc0 = 0.0f, acc1 = 0.0f, acc2 = 0.0f;
    #pragma unroll
    for (int i = 0; i < UPR; ++i) {
        int x0, y0; float wx, wy;
        sample_coords(r * sn + l0, r * cs + l1, x0, y0, wx, wy);
        r *= ratio;

        const u16* base = xb4 + ((size_t)(y0 * IMG + x0)) * 4;
        const ushort4 a00 = *(const ushort4*)(base);
        const ushort4 a01 = *(const ushort4*)(base + 4);
        const ushort4 a10 = *(const ushort4*)(base + IMG * 4);
        const ushort4 a11 = *(const ushort4*)(base + IMG * 4 + 4);

        const float wx0 = 1.0f - wx, wy0 = 1.0f - wy;
        const float w00 = wx0 * wy0, w01 = wx * wy0;
        const float w10 = wx0 * wy,  w11 = wx * wy;

        acc0 += w00*bf2f(a00.x) + w01*bf2f(a01.x) + w10*bf2f(a10.x) + w11*bf2f(a11.x);
        acc1 += w00*bf2f(a00.y) + w01*bf2f(a01.y) + w10*bf2f(a10.y) + w11*bf2f(a11.y);
        acc2 += w00*bf2f(a00.z) + w01*bf2f(a01.z) + w10*bf2f(a10.z) + w11*bf2f(a11.z);
    }
    part[0 * Wg + tid] = acc0;
    part[1 * Wg + tid] = acc1;
    part[2 * Wg + tid] = acc2;
    __syncthreads();

    if (tid < Cn * Ww) {
        const int c = tid / Ww;
        const int w = tid % Ww;
        const float* p = part + c * Wg + w * UPT;
        float s = 0.0f;
        #pragma unroll
        for (int j = 0; j < UPT; ++j) s += p[j];
        out[(((size_t)b * Cn + c) * Hh + h) * Ww + w] = s * (1.0f / (UPR * UPT));
    }
}

// -------------------------------------------------------------------------
// Fallback path (ws too small for x4b): k2 head + NCHW fp32 sampler.
// -------------------------------------------------------------------------
__global__ __launch_bounds__(256) void k2_head(
    const float* __restrict__ partial, const float* __restrict__ w2,
    const float* __restrict__ b2, const float* __restrict__ fc1w,
    const float* __restrict__ fc1b, const float* __restrict__ fc2w,
    const float* __restrict__ fc2b, float* __restrict__ wt_ws,
    float* __restrict__ out)
{
    const int b = blockIdx.x;
    const int tid = threadIdx.x;
    __shared__ float wsb[150];
    __shared__ float sfeat[16];
    __shared__ float sh[8];

    if (tid < 150) {
        const float* p = partial + (size_t)b * PCHUNK * PSTRIDE + tid;
        float s = 0.0f;
        #pragma unroll 8
        for (int c = 0; c < PCHUNK; ++c) s += p[c * PSTRIDE];
        wsb[tid] = s;
    }
    __syncthreads();
    if (tid < 16) {
        float s = 0.0f;
        for (int j = 0; j < 150; ++j) s += w2[tid * 150 + j] * wsb[j];
        sfeat[tid] = b2[tid] + s * (1.0f / (float)NVALID);
    }
    __syncthreads();
    if (tid < 8) {
        float s = fc1b[tid];
        #pragma unroll
        for (int j = 0; j < 16; ++j) s += fc1w[tid * 16 + j] * sfeat[j];
        sh[tid] = fmaxf(s, 0.0f);
    }
    __syncthreads();
    if (tid < 2) {
        float s = fc2b[tid];
        #pragma unroll
        for (int j = 0; j < 8; ++j) s += fc2w[tid * 8 + j] * sh[j];
        float sig = (s >= 0.0f) ? (1.0f / (1.0f + expf(-s)))
                                : (expf(s) / (1.0f + expf(s)));
        const float wgt = 5.0f * sig;
        wt_ws[b * 2 + tid] = wgt;
        out[POOLED_SIZE + b * 2 + tid] = wgt;
    }
}

__global__ __launch_bounds__(640) void k3_sample_pool_nchw(
    const float* __restrict__ x, const float* __restrict__ ltp,
    const float* __restrict__ wt, float* __restrict__ out)
{
    __shared__ float part[3 * Wg];
    const int L = blockIdx.x;
    const int qq = L >> 3;
    const int h = qq & 31;
    const int b = (L & 7) + 8 * (qq >> 5);
    const int tid = threadIdx.x;

    const float w0 = wt[b * 2 + 0];
    const float w1 = wt[b * 2 + 1];
    const float l0 = ltp[b * 2 + 0];
    const float l1 = ltp[b * 2 + 1];
    const float start = logf(0.01f * w0);
    const float stop  = logf(0.6f  * w1);
    const float dr = stop - start;
    const float angle = 6.283185307179586f * (float)tid / (float)Wg;
    const float sn = sinf(angle);
    const float cs = cosf(angle);
    const float* xb = x + (size_t)b * Cn * PLANE;

    const float ratio = expf(dr * (1.0f / (float)(Hg - 1)));
    float r = expf(start + dr * ((float)(h * UPR) / (float)(Hg - 1)));

    float acc0 = 0.0f, acc1 = 0.0f, acc2 = 0.0f;
    #pragma unroll
    for (int i = 0; i < UPR; ++i) {
        int x0, y0; float wx, wy;
        sample_coords(r * sn + l0, r * cs + l1, x0, y0, wx, wy);
        r *= ratio;
        const float wx0 = 1.0f - wx, wy0 = 1.0f - wy;
        const float w00 = wx0 * wy0, w01 = wx * wy0;
        const float w10 = wx0 * wy,  w11 = wx * wy;
        const int o00 = y0 * IMG + x0;
        acc0 += w00*xb[o00] + w01*xb[o00+1] + w10*xb[o00+IMG] + w11*xb[o00+IMG+1];
        const float* x1p = xb + PLANE;
        acc1 += w00*x1p[o00] + w01*x1p[o00+1] + w10*x1p[o00+IMG] + w11*x1p[o00+IMG+1];
        const float* x2p = xb + 2 * PLANE;
        acc2 += w00*x2p[o00] + w01*x2p[o00+1] + w10*x2p[o00+IMG] + w11*x2p[o00+IMG+1];
    }
    part[0 * Wg + tid] = acc0;
    part[1 * Wg + tid] = acc1;
    part[2 * Wg + tid] = acc2;
    __syncthreads();

    if (tid < Cn * Ww) {
        const int c = tid / Ww;
        const int w = tid % Ww;
        const float* p = part + c * Wg + w * UPT;
        float s = 0.0f;
        #pragma unroll
        for (int j = 0; j < UPT; ++j) s += p[j];
        out[(((size_t)b * Cn + c) * Hh + h) * Ww + w] = s * (1.0f / (UPR * UPT));
    }
}

// -------------------------------------------------------------------------
extern "C" void kernel_launch(void* const* d_in, const int* in_sizes, int n_in,
                              void* d_out, int out_size, void* d_ws, size_t ws_size,
                              hipStream_t stream) {
    const float* x       = (const float*)d_in[0];
    const float* ltp     = (const float*)d_in[1];
    const float* conv1_w = (const float*)d_in[2];
    const float* conv1_b = (const float*)d_in[3];
    const float* conv2_w = (const float*)d_in[4];
    const float* conv2_b = (const float*)d_in[5];
    const float* fc1_w   = (const float*)d_in[6];
    const float* fc1_b   = (const float*)d_in[7];
    const float* fc2_w   = (const float*)d_in[8];
    const float* fc2_b   = (const float*)d_in[9];
    float* out = (float*)d_out;

    const int do_pack = (ws_size >= WS_NEEDED) ? 1 : 0;

    float* part_ws = (float*)d_ws;                // B*112*PSTRIDE
    float* wt_ws   = part_ws + PART_FLOATS;       // B*2 (fallback only)
    u16*   x4b     = (u16*)(wt_ws + Bn * 2);      // 8B-aligned

    k1_fused<<<dim3(14, Bn), dim3(256), 0, stream>>>(
        x, conv1_w, conv1_b, part_ws, x4b, do_pack);

    if (do_pack) {
        k3_fused<<<dim3(Hh * Bn), dim3(Wg), 0, stream>>>(
            x4b, ltp, part_ws, conv2_w, conv2_b,
            fc1_w, fc1_b, fc2_w, fc2_b, out);
    } else {
        k2_head<<<dim3(Bn), dim3(256), 0, stream>>>(part_ws, conv2_w, conv2_b,
                                                    fc1_w, fc1_b, fc2_w, fc2_b,
                                                    wt_ws, out);
        k3_sample_pool_nchw<<<dim3(Hh * Bn), dim3(Wg), 0, stream>>>(x, ltp, wt_ws, out);
    }
}

// Round 10
// 188.470 us; speedup vs baseline: 1.0175x; 1.0175x over previous
//
#include <hip/hip_runtime.h>
#include <math.h>

// Problem constants
#define Bn    64
#define Cn    3
#define IMG   224
#define PLANE (IMG*IMG)      // 50176
#define C1    6
#define P1    110            // conv1(220) + maxpool2 -> 110
#define P2    106            // conv2 output spatial
#define NVALID (P2*P2)       // 11236
#define Hh    32
#define Ww    64
#define UPR   10
#define UPT   10
#define Hg    (Hh*UPR)       // 320
#define Wg    (Ww*UPT)       // 640
#define POOLED_SIZE (Bn*Cn*Hh*Ww)   // 393216
#define RPB   4              // pooled rows per chunk (1 per wave, 4 waves)
#define NCHUNK 28
#define PCHUNK (NCHUNK * RPB)           // 112 per-wave partial slots
#define PSTRIDE 152

typedef unsigned short u16;
typedef unsigned int   u32;
typedef float v2f __attribute__((ext_vector_type(2)));

// workspace: partials (B*112*152 f32) | wt (B*2 f32, fallback only) | x4b bf16
#define PART_FLOATS ((size_t)Bn * PCHUNK * PSTRIDE)
#define X4B_U16     ((size_t)Bn * PLANE * 4)
#define WS_NEEDED   ((PART_FLOATS + Bn * 2) * 4 + X4B_U16 * 2)

__device__ __forceinline__ u16 f2bf(float f) {
    union { u32 u; float f; } c; c.f = f;
    u32 r = c.u + 0x7fffu + ((c.u >> 16) & 1u);   // RNE
    return (u16)(r >> 16);
}
__device__ __forceinline__ float bf2f(u16 v) {
    union { u32 u; float f; } c; c.u = ((u32)v) << 16;
    return c.f;
}

// 7 overlapping pairs P[j] = (r[j], r[j+1]) from an 8-float LDS row segment.
__device__ __forceinline__ void load_pairs(v2f* P, const float* rp) {
    const float4 a = *(const float4*)rp;
    const float4 c = *(const float4*)(rp + 4);
    P[0] = (v2f){a.x, a.y};
    P[1] = (v2f){a.y, a.z};
    P[2] = (v2f){a.z, a.w};
    P[3] = (v2f){a.w, c.x};
    P[4] = (v2f){c.x, c.y};
    P[5] = (v2f){c.y, c.z};
    P[6] = (v2f){c.z, c.w};
}

// -------------------------------------------------------------------------
// K1 (R8-proven 61.5 µs): fused conv1 (6 OCs, v_pk_fma_f32) + maxpool2 +
// bf16-NHWC4 repack + shuffle window sums -> per-WAVE partials.
// 12-row staging per half, 2 halves per block, LDS 32256 -> 5 blocks/CU.
// DO NOT enlarge LDS/staging: R5 (RPB=8) and R9 (20-row single-stage) both
// regressed 1.8-2.4x — this kernel lives on block-level interleaving.
// -------------------------------------------------------------------------
__global__ __launch_bounds__(256) void k1_fused(
    const float* __restrict__ x,      // (B,3,224,224)
    const float* __restrict__ w1,     // (6,3,5,5)
    const float* __restrict__ b1,     // (6,)
    float* __restrict__ partial,      // (B,112,PSTRIDE) per-wave
    u16* __restrict__ x4b,            // (B,224,224,4) bf16 out
    int do_pack)
{
    __shared__ __attribute__((aligned(16))) float xs[3][12][224];  // 32256 B

    const int b    = blockIdx.y;
    const int tid  = threadIdx.x;
    const int wid  = tid >> 6;
    const int lane = tid & 63;

    const float* xb = x + (size_t)b * (Cn * PLANE);

    for (int half = 0; half < 2; ++half) {
        const int chunk = 2 * blockIdx.x + half;
        const int y0 = chunk * RPB;
        const int gybase = 2 * y0;

        // stage 12 input rows x 3 ic, coalesced float4
        for (int i = tid; i < 3 * 12 * 56; i += 256) {
            const int ic  = i / (12 * 56);
            const int rem = i - ic * (12 * 56);
            const int r   = rem / 56;
            const int c4  = rem - r * 56;
            const int gy  = gybase + r;
            if (gy < IMG)
                *(float4*)(&xs[ic][r][c4 * 4]) =
                    *(const float4*)(xb + ic * PLANE + gy * IMG + c4 * 4);
        }
        __syncthreads();

        // bf16 NHWC4 pack of this chunk's 8 owned rows (28 chunks x 8 = 224)
        if (do_pack) {
            u16* ob = x4b + (size_t)b * PLANE * 4;
            for (int i = tid; i < 8 * IMG; i += 256) {
                const int r   = i / IMG;
                const int col = i - r * IMG;
                const int gy  = gybase + r;
                ushort4 v;
                v.x = f2bf(xs[0][r][col]);
                v.y = f2bf(xs[1][r][col]);
                v.z = f2bf(xs[2][r][col]);
                v.w = 0;
                *(ushort4*)(ob + ((size_t)gy * IMG + col) * 4) = v;
            }
        }

        const int y = y0 + wid;
        const bool rowvalid = (y < P1);
        const bool active = (lane < 55) && rowvalid;

        float pp0[C1], pp1[C1];
        if (active) {
            v2f accT01[C1], accT23[C1], accB01[C1], accB23[C1];
            #pragma unroll
            for (int oc = 0; oc < C1; ++oc) {
                const float bv = b1[oc];
                const v2f bvv = (v2f){bv, bv};
                accT01[oc] = bvv; accT23[oc] = bvv;
                accB01[oc] = bvv; accB23[oc] = bvv;
            }

            #pragma unroll
            for (int ic = 0; ic < 3; ++ic) {
                v2f Pa[7], Pb[7];
                load_pairs(Pa, &xs[ic][2 * wid][4 * lane]);
                load_pairs(Pb, &xs[ic][2 * wid + 1][4 * lane]);
                #pragma unroll
                for (int ky = 0; ky < 5; ++ky) {
                    const v2f* Pt = (ky & 1) ? Pb : Pa;   // conv row 2y+ky
                    const v2f* Po = (ky & 1) ? Pa : Pb;   // conv row 2y+ky+1
                    #pragma unroll
                    for (int oc = 0; oc < C1; ++oc) {
                        const float* wrow = w1 + ((oc * 3 + ic) * 25 + ky * 5);
                        #pragma unroll
                        for (int kx = 0; kx < 5; ++kx) {
                            const float wv = wrow[kx];     // uniform s_load
                            const v2f wvv = (v2f){wv, wv};
                            accT01[oc] += Pt[kx]     * wvv;  // v_pk_fma_f32
                            accT23[oc] += Pt[kx + 2] * wvv;
                            accB01[oc] += Po[kx]     * wvv;
                            accB23[oc] += Po[kx + 2] * wvv;
                        }
                    }
                    if (ky < 4)
                        load_pairs((ky & 1) ? Pb : Pa,
                                   &xs[ic][2 * wid + ky + 2][4 * lane]);
                }
            }

            #pragma unroll
            for (int oc = 0; oc < C1; ++oc) {
                pp0[oc] = fmaxf(fmaxf(accT01[oc].x, accT01[oc].y),
                                fmaxf(accB01[oc].x, accB01[oc].y));
                pp1[oc] = fmaxf(fmaxf(accT23[oc].x, accT23[oc].y),
                                fmaxf(accB23[oc].x, accB23[oc].y));
            }
        } else {
            #pragma unroll
            for (int oc = 0; oc < C1; ++oc) { pp0[oc] = 0.0f; pp1[oc] = 0.0f; }
        }

        // Wave-level windowed row sums -> per-wave global partial slot.
        float* dst = partial + ((size_t)b * PCHUNK + chunk * RPB + wid) * PSTRIDE;
        #pragma unroll
        for (int oc = 0; oc < C1; ++oc) {
            float s = pp0[oc] + pp1[oc];
            #pragma unroll
            for (int off = 32; off > 0; off >>= 1) s += __shfl_xor(s, off, 64);
            const float c0   = __shfl(pp0[oc], 0, 64);
            const float c1   = __shfl(pp1[oc], 0, 64);
            const float c2   = __shfl(pp0[oc], 1, 64);
            const float c3   = __shfl(pp1[oc], 1, 64);
            const float c106 = __shfl(pp0[oc], 53, 64);
            const float c107 = __shfl(pp1[oc], 53, 64);
            const float c108 = __shfl(pp0[oc], 54, 64);
            const float c109 = __shfl(pp1[oc], 54, 64);
            const float w0v = s - (c106 + c107 + c108 + c109);
            const float w1v = s - c0 - (c107 + c108 + c109);
            const float w2v = s - (c0 + c1) - (c108 + c109);
            const float w3v = s - (c0 + c1 + c2) - c109;
            const float w4v = s - (c0 + c1 + c2 + c3);
            if (lane < 25) {
                const int ky = lane / 5;
                const int kx = lane % 5;
                float wv = w0v;
                wv = (kx == 1) ? w1v : wv;
                wv = (kx == 2) ? w2v : wv;
                wv = (kx == 3) ? w3v : wv;
                wv = (kx == 4) ? w4v : wv;
                const bool valid = rowvalid && ((unsigned)(y - ky) <= 105u);
                dst[oc * 25 + lane] = valid ? wv : 0.0f;
            }
        }
        __syncthreads();   // xs reuse guard for next half's staging
    }
}

// -------------------------------------------------------------------------
// Clamp-coordinate sampling (equivalent to corner-clamp border mode).
// -------------------------------------------------------------------------
__device__ __forceinline__ void sample_coords(
    float gxn, float gyn, int& x0, int& y0, float& wx, float& wy)
{
    float ix = ((gxn + 1.0f) * (float)IMG - 1.0f) * 0.5f;
    float iy = ((gyn + 1.0f) * (float)IMG - 1.0f) * 0.5f;
    ix = fminf(fmaxf(ix, 0.0f), (float)(IMG - 1));
    iy = fminf(fmaxf(iy, 0.0f), (float)(IMG - 1));
    x0 = (int)ix; if (x0 > IMG - 2) x0 = IMG - 2;
    y0 = (int)iy; if (y0 > IMG - 2) y0 = IMG - 2;
    wx = ix - (float)x0;
    wy = iy - (float)y0;
}

// -------------------------------------------------------------------------
// K3 (R9-proven ~40 µs): fused head (112-partial reduce + MLP, redundant
// per-b) + bf16 NHWC4 sample + pool. XCD swizzle b=(L&7)+8*(L>>8).
// ushort4 loads, fast transcendentals.
// -------------------------------------------------------------------------
__global__ __launch_bounds__(640) void k3_fused(
    const u16* __restrict__ x4b,      // (B,224,224,4) bf16
    const float* __restrict__ ltp,
    const float* __restrict__ partial,
    const float* __restrict__ w2, const float* __restrict__ b2,
    const float* __restrict__ fc1w, const float* __restrict__ fc1b,
    const float* __restrict__ fc2w, const float* __restrict__ fc2b,
    float* __restrict__ out)
{
    __shared__ float part[3 * Wg];    // 7680 B
    __shared__ float red[4][150];     // 2400 B
    __shared__ float wsb[150];
    __shared__ float wt2[2];

    const int L = blockIdx.x;         // 0..2047
    const int qq = L >> 3;            // 0..255
    const int h = qq & 31;
    const int b = (L & 7) + 8 * (qq >> 5);
    const int tid = threadIdx.x;

    // Per-thread trig first (independent of head result)
    const float angle = 6.283185307179586f * (float)tid / (float)Wg;
    const float sn = __sinf(angle);
    const float cs = __cosf(angle);

    // ---- fused head: reduce 112 per-wave partials (4 groups x 28) ----
    if (tid < 600) {
        const int g = tid / 150;
        const int e = tid - g * 150;
        const float* p = partial + ((size_t)b * PCHUNK + g * 28) * PSTRIDE + e;
        float s = 0.0f;
        #pragma unroll 7
        for (int c = 0; c < 28; ++c) s += p[c * PSTRIDE];
        red[g][e] = s;
    }
    __syncthreads();
    if (tid < 150)
        wsb[tid] = red[0][tid] + red[1][tid] + red[2][tid] + red[3][tid];
    __syncthreads();
    if (tid < 64) {                   // wave 0 computes the MLP via shuffles
        const int fi = tid & 15;
        float s = 0.0f;
        for (int j = 0; j < 150; ++j) s += w2[fi * 150 + j] * wsb[j];
        const float feat = b2[fi] + s * (1.0f / (float)NVALID);
        const int hi = tid & 7;
        float s1 = fc1b[hi];
        #pragma unroll
        for (int j = 0; j < 16; ++j) s1 += fc1w[hi * 16 + j] * __shfl(feat, j, 64);
        const float hv = fmaxf(s1, 0.0f);
        const int oi = tid & 1;
        float s2 = fc2b[oi];
        #pragma unroll
        for (int j = 0; j < 8; ++j) s2 += fc2w[oi * 8 + j] * __shfl(hv, j, 64);
        const float sig = (s2 >= 0.0f) ? (1.0f / (1.0f + __expf(-s2)))
                                       : (__expf(s2) / (1.0f + __expf(s2)));
        const float wgt = 5.0f * sig;
        if (tid < 2) {
            wt2[tid] = wgt;
            if (h == 0) out[POOLED_SIZE + b * 2 + tid] = wgt;   // weight output
        }
    }
    __syncthreads();

    const float w0 = wt2[0];
    const float w1 = wt2[1];
    const float l0 = ltp[b * 2 + 0];
    const float l1 = ltp[b * 2 + 1];
    const float start = __logf(0.01f * w0);
    const float stop  = __logf(0.6f  * w1);
    const float dr = stop - start;

    const u16* xb4 = x4b + (size_t)b * PLANE * 4;

    const float ratio = __expf(dr * (1.0f / (float)(Hg - 1)));
    float r = __expf(start + dr * ((float)(h * UPR) / (float)(Hg - 1)));

    float acc0 = 0.0f, acc1 = 0.0f, acc2 = 0.0f;
    #pragma unroll
    for (int i = 0; i < UPR; ++i) {
        int x0, y0; float wx, wy;
        sample_coords(r * sn + l0, r * cs + l1, x0, y0, wx, wy);
        r *= ratio;

        const u16* base = xb4 + ((size_t)(y0 * IMG + x0)) * 4;
        const ushort4 a00 = *(const ushort4*)(base);
        const ushort4 a01 = *(const ushort4*)(base + 4);
        const ushort4 a10 = *(const ushort4*)(base + IMG * 4);
        const ushort4 a11 = *(const ushort4*)(base + IMG * 4 + 4);

        const float wx0 = 1.0f - wx, wy0 = 1.0f - wy;
        const float w00 = wx0 * wy0, w01 = wx * wy0;
        const float w10 = wx0 * wy,  w11 = wx * wy;

        acc0 += w00*bf2f(a00.x) + w01*bf2f(a01.x) + w10*bf2f(a10.x) + w11*bf2f(a11.x);
        acc1 += w00*bf2f(a00.y) + w01*bf2f(a01.y) + w10*bf2f(a10.y) + w11*bf2f(a11.y);
        acc2 += w00*bf2f(a00.z) + w01*bf2f(a01.z) + w10*bf2f(a10.z) + w11*bf2f(a11.z);
    }
    part[0 * Wg + tid] = acc0;
    part[1 * Wg + tid] = acc1;
    part[2 * Wg + tid] = acc2;
    __syncthreads();

    if (tid < Cn * Ww) {
        const int c = tid / Ww;
        const int w = tid % Ww;
        const float* p = part + c * Wg + w * UPT;
        float s = 0.0f;
        #pragma unroll
        for (int j = 0; j < UPT; ++j) s += p[j];
        out[(((size_t)b * Cn + c) * Hh + h) * Ww + w] = s * (1.0f / (UPR * UPT));
    }
}

// -------------------------------------------------------------------------
// Fallback path (ws too small for x4b): k2 head + NCHW fp32 sampler.
// -------------------------------------------------------------------------
__global__ __launch_bounds__(256) void k2_head(
    const float* __restrict__ partial, const float* __restrict__ w2,
    const float* __restrict__ b2, const float* __restrict__ fc1w,
    const float* __restrict__ fc1b, const float* __restrict__ fc2w,
    const float* __restrict__ fc2b, float* __restrict__ wt_ws,
    float* __restrict__ out)
{
    const int b = blockIdx.x;
    const int tid = threadIdx.x;
    __shared__ float wsb[150];
    __shared__ float sfeat[16];
    __shared__ float sh[8];

    if (tid < 150) {
        const float* p = partial + (size_t)b * PCHUNK * PSTRIDE + tid;
        float s = 0.0f;
        #pragma unroll 8
        for (int c = 0; c < PCHUNK; ++c) s += p[c * PSTRIDE];
        wsb[tid] = s;
    }
    __syncthreads();
    if (tid < 16) {
        float s = 0.0f;
        for (int j = 0; j < 150; ++j) s += w2[tid * 150 + j] * wsb[j];
        sfeat[tid] = b2[tid] + s * (1.0f / (float)NVALID);
    }
    __syncthreads();
    if (tid < 8) {
        float s = fc1b[tid];
        #pragma unroll
        for (int j = 0; j < 16; ++j) s += fc1w[tid * 16 + j] * sfeat[j];
        sh[tid] = fmaxf(s, 0.0f);
    }
    __syncthreads();
    if (tid < 2) {
        float s = fc2b[tid];
        #pragma unroll
        for (int j = 0; j < 8; ++j) s += fc2w[tid * 8 + j] * sh[j];
        float sig = (s >= 0.0f) ? (1.0f / (1.0f + expf(-s)))
                                : (expf(s) / (1.0f + expf(s)));
        const float wgt = 5.0f * sig;
        wt_ws[b * 2 + tid] = wgt;
        out[POOLED_SIZE + b * 2 + tid] = wgt;
    }
}

__global__ __launch_bounds__(640) void k3_sample_pool_nchw(
    const float* __restrict__ x, const float* __restrict__ ltp,
    const float* __restrict__ wt, float* __restrict__ out)
{
    __shared__ float part[3 * Wg];
    const int L = blockIdx.x;
    const int qq = L >> 3;
    const int h = qq & 31;
    const int b = (L & 7) + 8 * (qq >> 5);
    const int tid = threadIdx.x;

    const float w0 = wt[b * 2 + 0];
    const float w1 = wt[b * 2 + 1];
    const float l0 = ltp[b * 2 + 0];
    const float l1 = ltp[b * 2 + 1];
    const float start = logf(0.01f * w0);
    const float stop  = logf(0.6f  * w1);
    const float dr = stop - start;
    const float angle = 6.283185307179586f * (float)tid / (float)Wg;
    const float sn = sinf(angle);
    const float cs = cosf(angle);
    const float* xb = x + (size_t)b * Cn * PLANE;

    const float ratio = expf(dr * (1.0f / (float)(Hg - 1)));
    float r = expf(start + dr * ((float)(h * UPR) / (float)(Hg - 1)));

    float acc0 = 0.0f, acc1 = 0.0f, acc2 = 0.0f;
    #pragma unroll
    for (int i = 0; i < UPR; ++i) {
        int x0, y0; float wx, wy;
        sample_coords(r * sn + l0, r * cs + l1, x0, y0, wx, wy);
        r *= ratio;
        const float wx0 = 1.0f - wx, wy0 = 1.0f - wy;
        const float w00 = wx0 * wy0, w01 = wx * wy0;
        const float w10 = wx0 * wy,  w11 = wx * wy;
        const int o00 = y0 * IMG + x0;
        acc0 += w00*xb[o00] + w01*xb[o00+1] + w10*xb[o00+IMG] + w11*xb[o00+IMG+1];
        const float* x1p = xb + PLANE;
        acc1 += w00*x1p[o00] + w01*x1p[o00+1] + w10*x1p[o00+IMG] + w11*x1p[o00+IMG+1];
        const float* x2p = xb + 2 * PLANE;
        acc2 += w00*x2p[o00] + w01*x2p[o00+1] + w10*x2p[o00+IMG] + w11*x2p[o00+IMG+1];
    }
    part[0 * Wg + tid] = acc0;
    part[1 * Wg + tid] = acc1;
    part[2 * Wg + tid] = acc2;
    __syncthreads();

    if (tid < Cn * Ww) {
        const int c = tid / Ww;
        const int w = tid % Ww;
        const float* p = part + c * Wg + w * UPT;
        float s = 0.0f;
        #pragma unroll
        for (int j = 0; j < UPT; ++j) s += p[j];
        out[(((size_t)b * Cn + c) * Hh + h) * Ww + w] = s * (1.0f / (UPR * UPT));
    }
}

// -------------------------------------------------------------------------
extern "C" void kernel_launch(void* const* d_in, const int* in_sizes, int n_in,
                              void* d_out, int out_size, void* d_ws, size_t ws_size,
                              hipStream_t stream) {
    const float* x       = (const float*)d_in[0];
    const float* ltp     = (const float*)d_in[1];
    const float* conv1_w = (const float*)d_in[2];
    const float* conv1_b = (const float*)d_in[3];
    const float* conv2_w = (const float*)d_in[4];
    const float* conv2_b = (const float*)d_in[5];
    const float* fc1_w   = (const float*)d_in[6];
    const float* fc1_b   = (const float*)d_in[7];
    const float* fc2_w   = (const float*)d_in[8];
    const float* fc2_b   = (const float*)d_in[9];
    float* out = (float*)d_out;

    const int do_pack = (ws_size >= WS_NEEDED) ? 1 : 0;

    float* part_ws = (float*)d_ws;                // B*112*PSTRIDE
    float* wt_ws   = part_ws + PART_FLOATS;       // B*2 (fallback only)
    u16*   x4b     = (u16*)(wt_ws + Bn * 2);      // 8B-aligned

    k1_fused<<<dim3(NCHUNK / 2, Bn), dim3(256), 0, stream>>>(
        x, conv1_w, conv1_b, part_ws, x4b, do_pack);

    if (do_pack) {
        k3_fused<<<dim3(Hh * Bn), dim3(Wg), 0, stream>>>(
            x4b, ltp, part_ws, conv2_w, conv2_b,
            fc1_w, fc1_b, fc2_w, fc2_b, out);
    } else {
        k2_head<<<dim3(Bn), dim3(256), 0, stream>>>(part_ws, conv2_w, conv2_b,
                                                    fc1_w, fc1_b, fc2_w, fc2_b,
                                                    wt_ws, out);
        k3_sample_pool_nchw<<<dim3(Hh * Bn), dim3(Wg), 0, stream>>>(x, ltp, wt_ws, out);
    }
}

// Round 12
// 187.081 us; speedup vs baseline: 1.0251x; 1.0074x over previous
//
#include <hip/hip_runtime.h>
#include <math.h>

// Problem constants
#define Bn    64
#define Cn    3
#define IMG   224
#define PLANE (IMG*IMG)      // 50176
#define C1    6
#define P1    110            // conv1(220) + maxpool2 -> 110
#define P2    106            // conv2 output spatial
#define NVALID (P2*P2)       // 11236
#define Hh    32
#define Ww    64
#define UPR   10
#define UPT   10
#define Hg    (Hh*UPR)       // 320
#define Wg    (Ww*UPT)       // 640
#define POOLED_SIZE (Bn*Cn*Hh*Ww)   // 393216
#define RPB   4              // pooled rows per chunk (1 per wave, 4 waves)
#define NCHUNK 28
#define PCHUNK (NCHUNK * RPB)           // 112 per-wave partial slots
#define PSTRIDE 152

typedef unsigned short u16;
typedef unsigned int   u32;
typedef float v2f __attribute__((ext_vector_type(2)));

// workspace: partials (B*112*152 f32) | wt (B*2 f32, fallback only) | x4b bf16
#define PART_FLOATS ((size_t)Bn * PCHUNK * PSTRIDE)
#define X4B_U16     ((size_t)Bn * PLANE * 4)
#define WS_NEEDED   ((PART_FLOATS + Bn * 2) * 4 + X4B_U16 * 2)

__device__ __forceinline__ u16 f2bf(float f) {
    union { u32 u; float f; } c; c.f = f;
    u32 r = c.u + 0x7fffu + ((c.u >> 16) & 1u);   // RNE
    return (u16)(r >> 16);
}
__device__ __forceinline__ float bf2f(u16 v) {
    union { u32 u; float f; } c; c.u = ((u32)v) << 16;
    return c.f;
}

// 7 overlapping pairs P[j] = (r[j], r[j+1]) from an 8-float LDS row segment.
__device__ __forceinline__ void load_pairs(v2f* P, const float* rp) {
    const float4 a = *(const float4*)rp;
    const float4 c = *(const float4*)(rp + 4);
    P[0] = (v2f){a.x, a.y};
    P[1] = (v2f){a.y, a.z};
    P[2] = (v2f){a.z, a.w};
    P[3] = (v2f){a.w, c.x};
    P[4] = (v2f){c.x, c.y};
    P[5] = (v2f){c.y, c.z};
    P[6] = (v2f){c.z, c.w};
}

// -------------------------------------------------------------------------
// K1 (R8-proven): fused conv1 (6 OCs, v_pk_fma_f32) + maxpool2 + bf16-NHWC4
// repack + shuffle window sums -> per-WAVE partials.
// 12-row staging per half, 2 halves per block, LDS 32256 -> 5 blocks/CU.
// DO NOT enlarge LDS/staging: R5 (RPB=8) and R9 (20-row single-stage) both
// regressed — this kernel lives on block-level interleaving.
// -------------------------------------------------------------------------
__global__ __launch_bounds__(256) void k1_fused(
    const float* __restrict__ x,      // (B,3,224,224)
    const float* __restrict__ w1,     // (6,3,5,5)
    const float* __restrict__ b1,     // (6,)
    float* __restrict__ partial,      // (B,112,PSTRIDE) per-wave
    u16* __restrict__ x4b,            // (B,224,224,4) bf16 out
    int do_pack)
{
    __shared__ __attribute__((aligned(16))) float xs[3][12][224];  // 32256 B

    const int b    = blockIdx.y;
    const int tid  = threadIdx.x;
    const int wid  = tid >> 6;
    const int lane = tid & 63;

    const float* xb = x + (size_t)b * (Cn * PLANE);

    for (int half = 0; half < 2; ++half) {
        const int chunk = 2 * blockIdx.x + half;
        const int y0 = chunk * RPB;
        const int gybase = 2 * y0;

        // stage 12 input rows x 3 ic, coalesced float4
        for (int i = tid; i < 3 * 12 * 56; i += 256) {
            const int ic  = i / (12 * 56);
            const int rem = i - ic * (12 * 56);
            const int r   = rem / 56;
            const int c4  = rem - r * 56;
            const int gy  = gybase + r;
            if (gy < IMG)
                *(float4*)(&xs[ic][r][c4 * 4]) =
                    *(const float4*)(xb + ic * PLANE + gy * IMG + c4 * 4);
        }
        __syncthreads();

        // bf16 NHWC4 pack of this chunk's 8 owned rows (28 chunks x 8 = 224)
        if (do_pack) {
            u16* ob = x4b + (size_t)b * PLANE * 4;
            for (int i = tid; i < 8 * IMG; i += 256) {
                const int r   = i / IMG;
                const int col = i - r * IMG;
                const int gy  = gybase + r;
                ushort4 v;
                v.x = f2bf(xs[0][r][col]);
                v.y = f2bf(xs[1][r][col]);
                v.z = f2bf(xs[2][r][col]);
                v.w = 0;
                *(ushort4*)(ob + ((size_t)gy * IMG + col) * 4) = v;
            }
        }

        const int y = y0 + wid;
        const bool rowvalid = (y < P1);
        const bool active = (lane < 55) && rowvalid;

        float pp0[C1], pp1[C1];
        if (active) {
            v2f accT01[C1], accT23[C1], accB01[C1], accB23[C1];
            #pragma unroll
            for (int oc = 0; oc < C1; ++oc) {
                const float bv = b1[oc];
                const v2f bvv = (v2f){bv, bv};
                accT01[oc] = bvv; accT23[oc] = bvv;
                accB01[oc] = bvv; accB23[oc] = bvv;
            }

            #pragma unroll
            for (int ic = 0; ic < 3; ++ic) {
                v2f Pa[7], Pb[7];
                load_pairs(Pa, &xs[ic][2 * wid][4 * lane]);
                load_pairs(Pb, &xs[ic][2 * wid + 1][4 * lane]);
                #pragma unroll
                for (int ky = 0; ky < 5; ++ky) {
                    const v2f* Pt = (ky & 1) ? Pb : Pa;   // conv row 2y+ky
                    const v2f* Po = (ky & 1) ? Pa : Pb;   // conv row 2y+ky+1
                    #pragma unroll
                    for (int oc = 0; oc < C1; ++oc) {
                        const float* wrow = w1 + ((oc * 3 + ic) * 25 + ky * 5);
                        #pragma unroll
                        for (int kx = 0; kx < 5; ++kx) {
                            const float wv = wrow[kx];     // uniform s_load
                            const v2f wvv = (v2f){wv, wv};
                            accT01[oc] += Pt[kx]     * wvv;  // v_pk_fma_f32
                            accT23[oc] += Pt[kx + 2] * wvv;
                            accB01[oc] += Po[kx]     * wvv;
                            accB23[oc] += Po[kx + 2] * wvv;
                        }
                    }
                    if (ky < 4)
                        load_pairs((ky & 1) ? Pb : Pa,
                                   &xs[ic][2 * wid + ky + 2][4 * lane]);
                }
            }

            #pragma unroll
            for (int oc = 0; oc < C1; ++oc) {
                pp0[oc] = fmaxf(fmaxf(accT01[oc].x, accT01[oc].y),
                                fmaxf(accB01[oc].x, accB01[oc].y));
                pp1[oc] = fmaxf(fmaxf(accT23[oc].x, accT23[oc].y),
                                fmaxf(accB23[oc].x, accB23[oc].y));
            }
        } else {
            #pragma unroll
            for (int oc = 0; oc < C1; ++oc) { pp0[oc] = 0.0f; pp1[oc] = 0.0f; }
        }

        // Wave-level windowed row sums -> per-wave global partial slot.
        float* dst = partial + ((size_t)b * PCHUNK + chunk * RPB + wid) * PSTRIDE;
        #pragma unroll
        for (int oc = 0; oc < C1; ++oc) {
            float s = pp0[oc] + pp1[oc];
            #pragma unroll
            for (int off = 32; off > 0; off >>= 1) s += __shfl_xor(s, off, 64);
            const float c0   = __shfl(pp0[oc], 0, 64);
            const float c1   = __shfl(pp1[oc], 0, 64);
            const float c2   = __shfl(pp0[oc], 1, 64);
            const float c3   = __shfl(pp1[oc], 1, 64);
            const float c106 = __shfl(pp0[oc], 53, 64);
            const float c107 = __shfl(pp1[oc], 53, 64);
            const float c108 = __shfl(pp0[oc], 54, 64);
            const float c109 = __shfl(pp1[oc], 54, 64);
            const float w0v = s - (c106 + c107 + c108 + c109);
            const float w1v = s - c0 - (c107 + c108 + c109);
            const float w2v = s - (c0 + c1) - (c108 + c109);
            const float w3v = s - (c0 + c1 + c2) - c109;
            const float w4v = s - (c0 + c1 + c2 + c3);
            if (lane < 25) {
                const int ky = lane / 5;
                const int kx = lane % 5;
                float wv = w0v;
                wv = (kx == 1) ? w1v : wv;
                wv = (kx == 2) ? w2v : wv;
                wv = (kx == 3) ? w3v : wv;
                wv = (kx == 4) ? w4v : wv;
                const bool valid = rowvalid && ((unsigned)(y - ky) <= 105u);
                dst[oc * 25 + lane] = valid ? wv : 0.0f;
            }
        }
        __syncthreads();   // xs reuse guard for next half's staging
    }
}

// -------------------------------------------------------------------------
// Clamp-coordinate sampling (equivalent to corner-clamp border mode).
// -------------------------------------------------------------------------
__device__ __forceinline__ void sample_coords(
    float gxn, float gyn, int& x0, int& y0, float& wx, float& wy)
{
    float ix = ((gxn + 1.0f) * (float)IMG - 1.0f) * 0.5f;
    float iy = ((gyn + 1.0f) * (float)IMG - 1.0f) * 0.5f;
    ix = fminf(fmaxf(ix, 0.0f), (float)(IMG - 1));
    iy = fminf(fmaxf(iy, 0.0f), (float)(IMG - 1));
    x0 = (int)ix; if (x0 > IMG - 2) x0 = IMG - 2;
    y0 = (int)iy; if (y0 > IMG - 2) y0 = IMG - 2;
    wx = ix - (float)x0;
    wy = iy - (float)y0;
}

// -------------------------------------------------------------------------
// K3 (fused head + patch-mapped gather, NO LDS trig table — R11 crashed and
// the table was the only unexonerated construct; trig now in registers).
// Wave's 64 lanes cover a 16-angle x 4-radius patch per load instruction
// (lane = aq + 16*rq) instead of a 64-angle arc. Thread: 4 angles (g loop)
// x radii {rq,4+rq,8+rq} (masked at ridx>=10); shfl_xor(16,32) folds the 4
// rq groups; rq==0 lanes write per-angle sums to LDS. Head fused as in R9.
// -------------------------------------------------------------------------
__global__ __launch_bounds__(640) void k3_fused(
    const u16* __restrict__ x4b,      // (B,224,224,4) bf16
    const float* __restrict__ ltp,
    const float* __restrict__ partial,
    const float* __restrict__ w2, const float* __restrict__ b2,
    const float* __restrict__ fc1w, const float* __restrict__ fc1b,
    const float* __restrict__ fc2w, const float* __restrict__ fc2b,
    float* __restrict__ out)
{
    __shared__ float pacc[3][Wg];     // 7680 B per-angle accumulators
    __shared__ float red[4][150];     // 2400 B
    __shared__ float wsb[150];
    __shared__ float wt2[2];

    const int L = blockIdx.x;         // 0..2047
    const int qq = L >> 3;            // 0..255
    const int h = qq & 31;
    const int b = (L & 7) + 8 * (qq >> 5);
    const int tid = threadIdx.x;
    const int wv   = tid >> 6;        // wave 0..9
    const int lane = tid & 63;
    const int aq   = lane & 15;       // angle within patch
    const int rq   = lane >> 4;       // radius phase 0..3

    // ---- fused head: reduce 112 per-wave partials (4 groups x 28) ----
    if (tid < 600) {
        const int g = tid / 150;
        const int e = tid - g * 150;
        const float* p = partial + ((size_t)b * PCHUNK + g * 28) * PSTRIDE + e;
        float s = 0.0f;
        #pragma unroll 7
        for (int c = 0; c < 28; ++c) s += p[c * PSTRIDE];
        red[g][e] = s;
    }
    __syncthreads();
    if (tid < 150)
        wsb[tid] = red[0][tid] + red[1][tid] + red[2][tid] + red[3][tid];
    __syncthreads();
    if (tid < 64) {                   // wave 0 computes the MLP via shuffles
        const int fi = tid & 15;
        float s = 0.0f;
        for (int j = 0; j < 150; ++j) s += w2[fi * 150 + j] * wsb[j];
        const float feat = b2[fi] + s * (1.0f / (float)NVALID);
        const int hi = tid & 7;
        float s1 = fc1b[hi];
        #pragma unroll
        for (int j = 0; j < 16; ++j) s1 += fc1w[hi * 16 + j] * __shfl(feat, j, 64);
        const float hv = fmaxf(s1, 0.0f);
        const int oi = tid & 1;
        float s2 = fc2b[oi];
        #pragma unroll
        for (int j = 0; j < 8; ++j) s2 += fc2w[oi * 8 + j] * __shfl(hv, j, 64);
        const float sig = (s2 >= 0.0f) ? (1.0f / (1.0f + __expf(-s2)))
                                       : (__expf(s2) / (1.0f + __expf(s2)));
        const float wgt = 5.0f * sig;
        if (tid < 2) {
            wt2[tid] = wgt;
            if (h == 0) out[POOLED_SIZE + b * 2 + tid] = wgt;   // weight output
        }
    }
    __syncthreads();

    const float w0 = wt2[0];
    const float w1 = wt2[1];
    const float l0 = ltp[b * 2 + 0];
    const float l1 = ltp[b * 2 + 1];
    const float start = __logf(0.01f * w0);
    const float stop  = __logf(0.6f  * w1);
    const float dr = stop - start;
    const float inv = 1.0f / (float)(Hg - 1);

    // radii for this thread's phase: ridx = 4j + rq, j = 0..2 (masked >= 10)
    float rv[3];
    #pragma unroll
    for (int j = 0; j < 3; ++j) {
        const int ridx = 4 * j + rq;
        rv[j] = __expf(start + dr * ((float)(h * UPR + ridx) * inv));
    }

    const u16* xb4 = x4b + (size_t)b * PLANE * 4;

    #pragma unroll
    for (int g = 0; g < 4; ++g) {
        const int tile = g * 10 + wv;           // 0..39
        const int angle = tile * 16 + aq;       // 0..639
        const float ang = 6.283185307179586f * (float)angle * (1.0f / (float)Wg);
        const float sn = __sinf(ang);
        const float cs = __cosf(ang);

        float a0 = 0.0f, a1 = 0.0f, a2 = 0.0f;
        #pragma unroll
        for (int j = 0; j < 3; ++j) {
            const int ridx = 4 * j + rq;
            if (ridx < UPR) {
                const float r = rv[j];
                int x0, y0; float wx, wy;
                sample_coords(r * sn + l0, r * cs + l1, x0, y0, wx, wy);

                const u16* base = xb4 + ((size_t)(y0 * IMG + x0)) * 4;
                const ushort4 c00 = *(const ushort4*)(base);
                const ushort4 c01 = *(const ushort4*)(base + 4);
                const ushort4 c10 = *(const ushort4*)(base + IMG * 4);
                const ushort4 c11 = *(const ushort4*)(base + IMG * 4 + 4);

                const float wx0 = 1.0f - wx, wy0 = 1.0f - wy;
                const float w00 = wx0 * wy0, w01 = wx * wy0;
                const float w10 = wx0 * wy,  w11 = wx * wy;

                a0 += w00*bf2f(c00.x) + w01*bf2f(c01.x) + w10*bf2f(c10.x) + w11*bf2f(c11.x);
                a1 += w00*bf2f(c00.y) + w01*bf2f(c01.y) + w10*bf2f(c10.y) + w11*bf2f(c11.y);
                a2 += w00*bf2f(c00.z) + w01*bf2f(c01.z) + w10*bf2f(c10.z) + w11*bf2f(c11.z);
            }
        }
        // fold the 4 radius-phase groups sharing this angle
        a0 += __shfl_xor(a0, 16, 64); a0 += __shfl_xor(a0, 32, 64);
        a1 += __shfl_xor(a1, 16, 64); a1 += __shfl_xor(a1, 32, 64);
        a2 += __shfl_xor(a2, 16, 64); a2 += __shfl_xor(a2, 32, 64);
        if (rq == 0) {
            pacc[0][angle] = a0;
            pacc[1][angle] = a1;
            pacc[2][angle] = a2;
        }
    }
    __syncthreads();

    if (tid < Cn * Ww) {
        const int c = tid / Ww;
        const int w = tid % Ww;
        const float* p = &pacc[c][w * UPT];
        float s = 0.0f;
        #pragma unroll
        for (int j = 0; j < UPT; ++j) s += p[j];
        out[(((size_t)b * Cn + c) * Hh + h) * Ww + w] = s * (1.0f / (UPR * UPT));
    }
}

// -------------------------------------------------------------------------
// Fallback path (ws too small for x4b): k2 head + NCHW fp32 sampler.
// -------------------------------------------------------------------------
__global__ __launch_bounds__(256) void k2_head(
    const float* __restrict__ partial, const float* __restrict__ w2,
    const float* __restrict__ b2, const float* __restrict__ fc1w,
    const float* __restrict__ fc1b, const float* __restrict__ fc2w,
    const float* __restrict__ fc2b, float* __restrict__ wt_ws,
    float* __restrict__ out)
{
    const int b = blockIdx.x;
    const int tid = threadIdx.x;
    __shared__ float wsb[150];
    __shared__ float sfeat[16];
    __shared__ float sh[8];

    if (tid < 150) {
        const float* p = partial + (size_t)b * PCHUNK * PSTRIDE + tid;
        float s = 0.0f;
        #pragma unroll 8
        for (int c = 0; c < PCHUNK; ++c) s += p[c * PSTRIDE];
        wsb[tid] = s;
    }
    __syncthreads();
    if (tid < 16) {
        float s = 0.0f;
        for (int j = 0; j < 150; ++j) s += w2[tid * 150 + j] * wsb[j];
        sfeat[tid] = b2[tid] + s * (1.0f / (float)NVALID);
    }
    __syncthreads();
    if (tid < 8) {
        float s = fc1b[tid];
        #pragma unroll
        for (int j = 0; j < 16; ++j) s += fc1w[tid * 16 + j] * sfeat[j];
        sh[tid] = fmaxf(s, 0.0f);
    }
    __syncthreads();
    if (tid < 2) {
        float s = fc2b[tid];
        #pragma unroll
        for (int j = 0; j < 8; ++j) s += fc2w[tid * 8 + j] * sh[j];
        float sig = (s >= 0.0f) ? (1.0f / (1.0f + expf(-s)))
                                : (expf(s) / (1.0f + expf(s)));
        const float wgt = 5.0f * sig;
        wt_ws[b * 2 + tid] = wgt;
        out[POOLED_SIZE + b * 2 + tid] = wgt;
    }
}

__global__ __launch_bounds__(640) void k3_sample_pool_nchw(
    const float* __restrict__ x, const float* __restrict__ ltp,
    const float* __restrict__ wt, float* __restrict__ out)
{
    __shared__ float part[3 * Wg];
    const int L = blockIdx.x;
    const int qq = L >> 3;
    const int h = qq & 31;
    const int b = (L & 7) + 8 * (qq >> 5);
    const int tid = threadIdx.x;

    const float w0 = wt[b * 2 + 0];
    const float w1 = wt[b * 2 + 1];
    const float l0 = ltp[b * 2 + 0];
    const float l1 = ltp[b * 2 + 1];
    const float start = logf(0.01f * w0);
    const float stop  = logf(0.6f  * w1);
    const float dr = stop - start;
    const float angle = 6.283185307179586f * (float)tid / (float)Wg;
    const float sn = sinf(angle);
    const float cs = cosf(angle);
    const float* xb = x + (size_t)b * Cn * PLANE;

    const float ratio = expf(dr * (1.0f / (float)(Hg - 1)));
    float r = expf(start + dr * ((float)(h * UPR) / (float)(Hg - 1)));

    float acc0 = 0.0f, acc1 = 0.0f, acc2 = 0.0f;
    #pragma unroll
    for (int i = 0; i < UPR; ++i) {
        int x0, y0; float wx, wy;
        sample_coords(r * sn + l0, r * cs + l1, x0, y0, wx, wy);
        r *= ratio;
        const float wx0 = 1.0f - wx, wy0 = 1.0f - wy;
        const float w00 = wx0 * wy0, w01 = wx * wy0;
        const float w10 = wx0 * wy,  w11 = wx * wy;
        const int o00 = y0 * IMG + x0;
        acc0 += w00*xb[o00] + w01*xb[o00+1] + w10*xb[o00+IMG] + w11*xb[o00+IMG+1];
        const float* x1p = xb + PLANE;
        acc1 += w00*x1p[o00] + w01*x1p[o00+1] + w10*x1p[o00+IMG] + w11*x1p[o00+IMG+1];
        const float* x2p = xb + 2 * PLANE;
        acc2 += w00*x2p[o00] + w01*x2p[o00+1] + w10*x2p[o00+IMG] + w11*x2p[o00+IMG+1];
    }
    part[0 * Wg + tid] = acc0;
    part[1 * Wg + tid] = acc1;
    part[2 * Wg + tid] = acc2;
    __syncthreads();

    if (tid < Cn * Ww) {
        const int c = tid / Ww;
        const int w = tid % Ww;
        const float* p = part + c * Wg + w * UPT;
        float s = 0.0f;
        #pragma unroll
        for (int j = 0; j < UPT; ++j) s += p[j];
        out[(((size_t)b * Cn + c) * Hh + h) * Ww + w] = s * (1.0f / (UPR * UPT));
    }
}

// -------------------------------------------------------------------------
extern "C" void kernel_launch(void* const* d_in, const int* in_sizes, int n_in,
                              void* d_out, int out_size, void* d_ws, size_t ws_size,
                              hipStream_t stream) {
    const float* x       = (const float*)d_in[0];
    const float* ltp     = (const float*)d_in[1];
    const float* conv1_w = (const float*)d_in[2];
    const float* conv1_b = (const float*)d_in[3];
    const float* conv2_w = (const float*)d_in[4];
    const float* conv2_b = (const float*)d_in[5];
    const float* fc1_w   = (const float*)d_in[6];
    const float* fc1_b   = (const float*)d_in[7];
    const float* fc2_w   = (const float*)d_in[8];
    const float* fc2_b   = (const float*)d_in[9];
    float* out = (float*)d_out;

    const int do_pack = (ws_size >= WS_NEEDED) ? 1 : 0;

    float* part_ws = (float*)d_ws;                // B*112*PSTRIDE
    float* wt_ws   = part_ws + PART_FLOATS;       // B*2 (fallback only)
    u16*   x4b     = (u16*)(wt_ws + Bn * 2);      // 8B-aligned

    k1_fused<<<dim3(NCHUNK / 2, Bn), dim3(256), 0, stream>>>(
        x, conv1_w, conv1_b, part_ws, x4b, do_pack);

    if (do_pack) {
        k3_fused<<<dim3(Hh * Bn), dim3(Wg), 0, stream>>>(
            x4b, ltp, part_ws, conv2_w, conv2_b,
            fc1_w, fc1_b, fc2_w, fc2_b, out);
    } else {
        k2_head<<<dim3(Bn), dim3(256), 0, stream>>>(part_ws, conv2_w, conv2_b,
                                                    fc1_w, fc1_b, fc2_w, fc2_b,
                                                    wt_ws, out);
        k3_sample_pool_nchw<<<dim3(Hh * Bn), dim3(Wg), 0, stream>>>(x, ltp, wt_ws, out);
    }
}